// Round 3
// baseline (355.045 us; speedup 1.0000x reference)
//
#include <hip/hip_runtime.h>
#include <hip/hip_bf16.h>
#include <stdint.h>

// Problem constants (fixed by the reference setup_inputs)
#define BATCH  16384
#define D_IN   1024
#define M_HID  4096
#define R_LORA 16
#define SCALING 2.0f   // ALPHA/R = 32/16

// R8: R5/R7 counters show an LLC-BW wall: wf demand at full MFMA util is
// 64 B/cyc/CU (39 TB/s aggregate) but wb (8.4 MB) misses the 4 MiB per-XCD
// L2, and the measured ~40% MfmaUtil in BOTH R5 (2 w/SIMD) and R7 (4 w/SIMD)
// implies the LLC serves ~15 TB/s. Occupancy was never the limiter (R7 null).
// Fix: col-halve blocks + pin halves to XCD halves (bid%8 = XCD, bit2 selects
// mhalf) so each XCD's wb working set is 4.2 MB ~ L2-resident; the stream is
// then L2-served (135 B/cyc/CU >> 64 demand). Wave geometry reverts to the
// spill-free R5 shape (512 thr, acc[2][2]). Outputs: k_init(out=b2) + one
// atomicAdd per row per col-half (no extra ws needed beyond wb's 8 MiB).
// Also: k_wprep v3 (separate dispatch, attributable): coalesced W0/A reads,
// B pre-scaled in LDS; bit-identical wb.

typedef __bf16 bf16x8 __attribute__((ext_vector_type(8)));
typedef float  f32x16 __attribute__((ext_vector_type(16)));

__device__ __forceinline__ unsigned f2bf(float f) {
    union { float f; unsigned u; } c; c.f = f;
    unsigned u = c.u;
    return ((u + 0x7FFFu + ((u >> 16) & 1u)) >> 16);
}

// ---------------- prep v3: W_eff -> fragment-ordered bf16 ----------------
// Layout (shorts): n32*32768 + c*256 + rl*8 holds W_eff[n32*32+rl][c*8 .. c*8+8).
// Block = one n32 x one col-half. W0 reads: 64 lanes x 32B contiguous per row
// (coalesced). A reads coalesced from L2 (64 KB resident). B pre-scaled into
// LDS (broadcast reads). Writes: 16B chunks at 512B stride (fire-and-forget).
__global__ __launch_bounds__(512) void k_wprep(
    const float* __restrict__ W0, const float* __restrict__ A,
    const float* __restrict__ Bl, unsigned short* __restrict__ wb)
{
    __shared__ float Bs[512];                     // 32 rows x 16 r, pre-scaled
    const int tid   = threadIdx.x;
    const int n32   = blockIdx.x >> 1;            // 0..127
    const int chalf = blockIdx.x & 1;
    const int col0  = chalf * 512;

    Bs[tid] = SCALING * Bl[n32 * 512 + tid];
    __syncthreads();

    const int lane = tid & 63;
    const int w    = tid >> 6;                    // 0..7
    const float* a_base = A + col0 + lane * 8;

#pragma unroll
    for (int j = 0; j < 4; ++j) {
        const int row = j * 8 + w;                // 0..31
        const int n   = n32 * 32 + row;
        const float* p = W0 + (size_t)n * D_IN + col0 + lane * 8;
        float4 v0 = *(const float4*)(p);
        float4 v1 = *(const float4*)(p + 4);
        const float* bsr = &Bs[row * 16];
#pragma unroll
        for (int r = 0; r < R_LORA; ++r) {
            float s = bsr[r];
            const float* ap = a_base + r * D_IN;
            float4 a0 = *(const float4*)(ap);
            float4 a1 = *(const float4*)(ap + 4);
            v0.x += s * a0.x; v0.y += s * a0.y; v0.z += s * a0.z; v0.w += s * a0.w;
            v1.x += s * a1.x; v1.y += s * a1.y; v1.z += s * a1.z; v1.w += s * a1.w;
        }
        uint4 o;
        o.x = f2bf(v0.x) | (f2bf(v0.y) << 16);
        o.y = f2bf(v0.z) | (f2bf(v0.w) << 16);
        o.z = f2bf(v1.x) | (f2bf(v1.y) << 16);
        o.w = f2bf(v1.z) | (f2bf(v1.w) << 16);
        *(uint4*)(&wb[(size_t)n32 * 32768 + (size_t)(chalf * 64 + lane) * 256 + row * 8]) = o;
    }
}

// ---------------- out = b2 broadcast (atomicAdd target) ----------------
__global__ __launch_bounds__(256) void k_init(
    const float* __restrict__ b2, float* __restrict__ out)
{
    out[blockIdx.x * 256 + threadIdx.x] = b2[0];
}

// ---------------- main fused kernel: 64 rows x 2048 cols, XCD-pinned ----------------
// As layout (shorts): row*1024 + ((oct ^ (row&31))<<3) -- measured 0 conflicts.
__global__ __launch_bounds__(512, 2) void k_strip(
    const float* __restrict__ xf, const unsigned short* __restrict__ wb,
    const float* __restrict__ b0, const float* __restrict__ W2,
    float* __restrict__ out)
{
    __shared__ unsigned short As[64 * 1024];   // 128 KiB
    __shared__ float red[8][64];               // 2 KiB wave-private fold rows

    const int tid  = threadIdx.x;
    const int lane = tid & 63;
    const int wave = tid >> 6;      // 0..7
    const int rl   = lane & 31;
    const int half = lane >> 5;

    const int bid   = blockIdx.x;                       // 0..511
    const int mhalf = (bid >> 2) & 1;                   // = bit2 of XCD id
    const int strip = (bid & 3) | ((bid >> 3) << 2);    // bijective, 0..255
    const int row0  = strip * 64;

    // zero the fold accumulator (covered by the staging barrier)
    ((float*)red)[tid] = 0.f;

    // ---- phase 1: x fp32 -> bf16 into resident LDS strip (coalesced) ----
    {
        const int so8 = tid & 127;          // K-octet 0..127
        const int rb  = tid >> 7;           // 0..3
        const float* xsrc = xf + (size_t)row0 * D_IN + so8 * 8;
#pragma unroll
        for (int j = 0; j < 16; ++j) {
            const int r = j * 4 + rb;
            const float* p = xsrc + (size_t)r * D_IN;
            float4 v0 = *(const float4*)(p);
            float4 v1 = *(const float4*)(p + 4);
            uint4 o;
            o.x = f2bf(v0.x) | (f2bf(v0.y) << 16);
            o.y = f2bf(v0.z) | (f2bf(v0.w) << 16);
            o.z = f2bf(v1.x) | (f2bf(v1.y) << 16);
            o.w = f2bf(v1.z) | (f2bf(v1.w) << 16);
            *(uint4*)(&As[r * 1024 + ((so8 ^ (r & 31)) << 3)]) = o;
        }
    }
    __syncthreads();   // the only barrier before the final reduce

    // ---- main: 4 passes x zero-barrier K-loop (this block's col-half) ----
    for (int pass = 0; pass < 4; ++pass) {
        const int n0 = mhalf * 2048 + pass * 512 + wave * 64;
        const float w2a = W2[n0 + rl],      b0a = b0[n0 + rl];
        const float w2b = W2[n0 + 32 + rl], b0b = b0[n0 + 32 + rl];
        const int n32 = n0 >> 5;
        const unsigned short* w0p = wb + (size_t)n32 * 32768 + half * 256 + rl * 8;
        const unsigned short* w1p = w0p + 32768;

        f32x16 acc[2][2] = {};
        bf16x8 wf0[4], wf1[4];
#pragma unroll
        for (int p = 0; p < 4; ++p) {              // distance-4 register prefetch
            wf0[p] = *(const bf16x8*)(w0p + p * 512);
            wf1[p] = *(const bf16x8*)(w1p + p * 512);
        }

        // main loop: unconditional prefetch (branch-free bodies)
#pragma unroll 4
        for (int kk = 0; kk < 60; ++kk) {
            const int cur = kk & 3;
            const int oc  = kk * 2 + half;
            bf16x8 af0 = *(const bf16x8*)(&As[rl * 1024 + ((oc ^ rl) << 3)]);
            bf16x8 af1 = *(const bf16x8*)(&As[(32 + rl) * 1024 + ((oc ^ rl) << 3)]);
            bf16x8 w0c = wf0[cur], w1c = wf1[cur];
            wf0[cur] = *(const bf16x8*)(w0p + (kk + 4) * 512);
            wf1[cur] = *(const bf16x8*)(w1p + (kk + 4) * 512);
            acc[0][0] = __builtin_amdgcn_mfma_f32_32x32x16_bf16(af0, w0c, acc[0][0], 0, 0, 0);
            acc[0][1] = __builtin_amdgcn_mfma_f32_32x32x16_bf16(af0, w1c, acc[0][1], 0, 0, 0);
            acc[1][0] = __builtin_amdgcn_mfma_f32_32x32x16_bf16(af1, w0c, acc[1][0], 0, 0, 0);
            acc[1][1] = __builtin_amdgcn_mfma_f32_32x32x16_bf16(af1, w1c, acc[1][1], 0, 0, 0);
        }
        // tail: consume the last 4 ring entries, no prefetch
#pragma unroll
        for (int kk = 60; kk < 64; ++kk) {
            const int cur = kk & 3;
            const int oc  = kk * 2 + half;
            bf16x8 af0 = *(const bf16x8*)(&As[rl * 1024 + ((oc ^ rl) << 3)]);
            bf16x8 af1 = *(const bf16x8*)(&As[(32 + rl) * 1024 + ((oc ^ rl) << 3)]);
            acc[0][0] = __builtin_amdgcn_mfma_f32_32x32x16_bf16(af0, wf0[cur], acc[0][0], 0, 0, 0);
            acc[0][1] = __builtin_amdgcn_mfma_f32_32x32x16_bf16(af0, wf1[cur], acc[0][1], 0, 0, 0);
            acc[1][0] = __builtin_amdgcn_mfma_f32_32x32x16_bf16(af1, wf0[cur], acc[1][0], 0, 0, 0);
            acc[1][1] = __builtin_amdgcn_mfma_f32_32x32x16_bf16(af1, wf1[cur], acc[1][1], 0, 0, 0);
        }

        // fold this pass: relu(h + b0) dot W2, shuffle-reduce the 32 col-lanes,
        // accumulate into this wave's private LDS row (no cross-wave races).
        // C/D layout (m74/m101): col = lane&31, row = (r&3) + 8*(r>>2) + 4*half
#pragma unroll
        for (int ti = 0; ti < 2; ++ti)
#pragma unroll
            for (int r = 0; r < 16; ++r) {
                float p = fmaxf(acc[ti][0][r] + b0a, 0.f) * w2a
                        + fmaxf(acc[ti][1][r] + b0b, 0.f) * w2b;
#pragma unroll
                for (int m = 1; m <= 16; m <<= 1)
                    p += __shfl_xor(p, m, 64);        // stays within each 32-half
                if (rl == 0)
                    red[wave][ti * 32 + (r & 3) + 8 * (r >> 2) + 4 * half] += p;
            }
    }

    __syncthreads();
    if (tid < 64) {
        float s = 0.f;
#pragma unroll
        for (int w = 0; w < 8; ++w) s += red[w][tid];
        atomicAdd(&out[row0 + tid], s);               // 2 adds/row (col-halves)
    }
}

// ---------------- naive fallback (correctness only; ws too small) ----------------
__global__ __launch_bounds__(256) void k_naive(
    const float* __restrict__ x, const float* __restrict__ W0,
    const float* __restrict__ b0, const float* __restrict__ A,
    const float* __restrict__ Bl, const float* __restrict__ W2,
    const float* __restrict__ b2, float* __restrict__ out)
{
    __shared__ float xs[D_IN];
    int b = blockIdx.x;
    for (int d = threadIdx.x; d < D_IN; d += 256) xs[d] = x[(size_t)b * D_IN + d];
    __syncthreads();
    float part = 0.f;
    for (int m = threadIdx.x; m < M_HID; m += 256) {
        float h = b0[m];
        const float* wr = W0 + (size_t)m * D_IN;
        const float* brow = Bl + m * R_LORA;
        for (int d = 0; d < D_IN; ++d) {
            float w = wr[d];
            for (int r = 0; r < R_LORA; ++r) w += SCALING * brow[r] * A[r * D_IN + d];
            h += xs[d] * w;
        }
        part += fmaxf(h, 0.f) * W2[m];
    }
    __shared__ float sred[256];
    sred[threadIdx.x] = part;
    __syncthreads();
    for (int s = 128; s > 0; s >>= 1) {
        if (threadIdx.x < s) sred[threadIdx.x] += sred[threadIdx.x + s];
        __syncthreads();
    }
    if (threadIdx.x == 0) out[b] = sred[0] + b2[0];
}

// ---------------- host ----------------
extern "C" void kernel_launch(void* const* d_in, const int* in_sizes, int n_in,
                              void* d_out, int out_size, void* d_ws, size_t ws_size,
                              hipStream_t stream) {
    const float* x  = (const float*)d_in[0];
    const float* W0 = (const float*)d_in[1];
    const float* b0 = (const float*)d_in[2];
    const float* A  = (const float*)d_in[3];
    const float* Bl = (const float*)d_in[4];
    const float* W2 = (const float*)d_in[5];
    const float* b2 = (const float*)d_in[6];
    float* out = (float*)d_out;

    const size_t wb_bytes = (size_t)M_HID * D_IN * 2;   // 8 MiB fragment-ordered W_eff
    if (ws_size >= wb_bytes) {
        unsigned short* wb = (unsigned short*)d_ws;
        hipLaunchKernelGGL(k_wprep, dim3(M_HID / 32 * 2), dim3(512), 0, stream,
                           W0, A, Bl, wb);
        hipLaunchKernelGGL(k_init, dim3(BATCH / 256), dim3(256), 0, stream,
                           b2, out);
        hipLaunchKernelGGL(k_strip, dim3(512), dim3(512), 0, stream,
                           x, wb, b0, W2, out);
    } else {
        hipLaunchKernelGGL(k_naive, dim3(BATCH), dim3(256), 0, stream,
                           x, W0, b0, A, Bl, W2, b2, out);
    }
}

// Round 5
// 347.195 us; speedup vs baseline: 1.0226x; 1.0226x over previous
//
#include <hip/hip_runtime.h>
#include <hip/hip_bf16.h>
#include <stdint.h>

// Problem constants (fixed by the reference setup_inputs)
#define BATCH  16384
#define D_IN   1024
#define M_HID  4096
#define R_LORA 16
#define SCALING 2.0f   // ALPHA/R = 32/16

// R10 = R9 resubmit with the compile-risk removed (container died before
// producing counters; the only new compile-surface in R9 was the symbolic
// hwreg inline asm). Theory unchanged: wf stream is LLC-BW-bound (~15 TB/s:
// R5 2.15GB/147us; R7 2x-TLP null => not latency). Fix: column QUARTERS
// (1024 cols = 2.0 MiB << 4 MiB L2) pinned to the block's REAL XCD via
// __builtin_amdgcn_s_getreg(HW_REG_XCC_ID) + per-quarter atomic ticket
// queues -- L2 residency by CAPACITY, independent of dispatch order.
// Correctness does NOT depend on the hwreg value: any q in 0..3 is valid;
// queues guarantee each (strip, quarter) job exactly once and provably
// terminate (4x256 slots == 1024 blocks). Inner loop = proven R5 body
// (92 VGPR, 0 bank conflicts, depth-4 wf ring). Output: out=b2 init in
// k_wprep + one atomicAdd per row per quarter (atomics harmless per R8).

// s_getreg imm: ID=20 (HW_REG_XCC_ID) | offset 0 <<6 | (32-1)<<11
#define HWREG_XCC_ID_IMM 63508

typedef __bf16 bf16x8 __attribute__((ext_vector_type(8)));
typedef float  f32x16 __attribute__((ext_vector_type(16)));

__device__ __forceinline__ unsigned f2bf(float f) {
    union { float f; unsigned u; } c; c.f = f;
    unsigned u = c.u;
    return ((u + 0x7FFFu + ((u >> 16) & 1u)) >> 16);
}

// ---------------- prep v3: W_eff -> fragment-ordered bf16 ----------------
// Layout (shorts): n32*32768 + c*256 + rl*8 holds W_eff[n32*32+rl][c*8 .. c*8+8).
// Also: initializes out = b2[0] (atomicAdd target) and zeroes the job queues.
__global__ __launch_bounds__(512) void k_wprep(
    const float* __restrict__ W0, const float* __restrict__ A,
    const float* __restrict__ Bl, const float* __restrict__ b2,
    unsigned short* __restrict__ wb, float* __restrict__ out, int* qctr)
{
    __shared__ float Bs[512];                     // 32 rows x 16 r, pre-scaled
    const int tid   = threadIdx.x;
    const int n32   = blockIdx.x >> 1;            // 0..127
    const int chalf = blockIdx.x & 1;
    const int col0  = chalf * 512;

    if (qctr != nullptr && blockIdx.x == 0 && tid < 4) qctr[tid] = 0;
    {   // out = b2 broadcast (blocks 0..31 cover all 16384 rows)
        int oid = blockIdx.x * 512 + tid;
        if (oid < BATCH) out[oid] = b2[0];
    }

    Bs[tid] = SCALING * Bl[n32 * 512 + tid];
    __syncthreads();

    const int lane = tid & 63;
    const int w    = tid >> 6;                    // 0..7
    const float* a_base = A + col0 + lane * 8;

#pragma unroll
    for (int j = 0; j < 4; ++j) {
        const int row = j * 8 + w;                // 0..31
        const int n   = n32 * 32 + row;
        const float* p = W0 + (size_t)n * D_IN + col0 + lane * 8;
        float4 v0 = *(const float4*)(p);
        float4 v1 = *(const float4*)(p + 4);
        const float* bsr = &Bs[row * 16];
#pragma unroll
        for (int r = 0; r < R_LORA; ++r) {
            float s = bsr[r];
            const float* ap = a_base + r * D_IN;
            float4 a0 = *(const float4*)(ap);
            float4 a1 = *(const float4*)(ap + 4);
            v0.x += s * a0.x; v0.y += s * a0.y; v0.z += s * a0.z; v0.w += s * a0.w;
            v1.x += s * a1.x; v1.y += s * a1.y; v1.z += s * a1.z; v1.w += s * a1.w;
        }
        uint4 o;
        o.x = f2bf(v0.x) | (f2bf(v0.y) << 16);
        o.y = f2bf(v0.z) | (f2bf(v0.w) << 16);
        o.z = f2bf(v1.x) | (f2bf(v1.y) << 16);
        o.w = f2bf(v1.z) | (f2bf(v1.w) << 16);
        *(uint4*)(&wb[(size_t)n32 * 32768 + (size_t)(chalf * 64 + lane) * 256 + row * 8]) = o;
    }
}

// ---------------- main fused kernel: 64 rows x 1024-col quarter, XCD-queued ----
// As layout (shorts): row*1024 + ((oct ^ (row&31))<<3) -- measured 0 conflicts.
__global__ __launch_bounds__(512, 2) void k_strip(
    const float* __restrict__ xf, const unsigned short* __restrict__ wb,
    const float* __restrict__ b0, const float* __restrict__ W2,
    float* __restrict__ out, int* __restrict__ qctr)
{
    __shared__ unsigned short As[64 * 1024];   // 128 KiB
    __shared__ float red[8][64];               // 2 KiB wave-private fold rows
    __shared__ int job_s;

    const int tid  = threadIdx.x;
    const int lane = tid & 63;
    const int wave = tid >> 6;      // 0..7
    const int rl   = lane & 31;
    const int half = lane >> 5;

    // ---- job grab: quarter pinned to this block's REAL XCD ----
    if (tid == 0) {
        unsigned xcc = (unsigned)__builtin_amdgcn_s_getreg(HWREG_XCC_ID_IMM);
        int q = (int)(xcc & 3u);
        int t = atomicAdd(&qctr[q], 1);
        while (t >= 256) {                 // overflow: steal (terminates; jobs==blocks)
            q = (q + 1) & 3;
            t = atomicAdd(&qctr[q], 1);
        }
        job_s = (q << 8) | t;
    }
    ((float*)red)[tid] = 0.f;
    __syncthreads();

    const int q     = job_s >> 8;          // column quarter 0..3
    const int strip = job_s & 255;         // 0..255
    const int row0  = strip * 64;

    // ---- phase 1: x fp32 -> bf16 into resident LDS strip (coalesced) ----
    {
        const int so8 = tid & 127;          // K-octet 0..127
        const int rb  = tid >> 7;           // 0..3
        const float* xsrc = xf + (size_t)row0 * D_IN + so8 * 8;
#pragma unroll
        for (int j = 0; j < 16; ++j) {
            const int r = j * 4 + rb;
            const float* p = xsrc + (size_t)r * D_IN;
            float4 v0 = *(const float4*)(p);
            float4 v1 = *(const float4*)(p + 4);
            uint4 o;
            o.x = f2bf(v0.x) | (f2bf(v0.y) << 16);
            o.y = f2bf(v0.z) | (f2bf(v0.w) << 16);
            o.z = f2bf(v1.x) | (f2bf(v1.y) << 16);
            o.w = f2bf(v1.z) | (f2bf(v1.w) << 16);
            *(uint4*)(&As[r * 1024 + ((so8 ^ (r & 31)) << 3)]) = o;
        }
    }
    __syncthreads();   // the only barrier before the final reduce

    float rowpart[2][16];
#pragma unroll
    for (int ti = 0; ti < 2; ++ti)
#pragma unroll
        for (int r = 0; r < 16; ++r) rowpart[ti][r] = 0.f;

    // ---- main: 2 passes x zero-barrier K-loop, cols = this XCD's quarter ----
    for (int pass = 0; pass < 2; ++pass) {
        const int n0 = q * 1024 + pass * 512 + wave * 64;
        const float w2a = W2[n0 + rl],      b0a = b0[n0 + rl];
        const float w2b = W2[n0 + 32 + rl], b0b = b0[n0 + 32 + rl];
        const int n32 = n0 >> 5;
        const unsigned short* w0p = wb + (size_t)n32 * 32768 + half * 256 + rl * 8;
        const unsigned short* w1p = w0p + 32768;

        f32x16 acc[2][2] = {};
        bf16x8 wf0[4], wf1[4];
#pragma unroll
        for (int p = 0; p < 4; ++p) {              // distance-4 register prefetch
            wf0[p] = *(const bf16x8*)(w0p + p * 512);
            wf1[p] = *(const bf16x8*)(w1p + p * 512);
        }

        // main loop: unconditional prefetch (branch-free bodies)
#pragma unroll 4
        for (int kk = 0; kk < 60; ++kk) {
            const int cur = kk & 3;
            const int oc  = kk * 2 + half;
            bf16x8 af0 = *(const bf16x8*)(&As[rl * 1024 + ((oc ^ rl) << 3)]);
            bf16x8 af1 = *(const bf16x8*)(&As[(32 + rl) * 1024 + ((oc ^ rl) << 3)]);
            bf16x8 w0c = wf0[cur], w1c = wf1[cur];
            wf0[cur] = *(const bf16x8*)(w0p + (kk + 4) * 512);
            wf1[cur] = *(const bf16x8*)(w1p + (kk + 4) * 512);
            acc[0][0] = __builtin_amdgcn_mfma_f32_32x32x16_bf16(af0, w0c, acc[0][0], 0, 0, 0);
            acc[0][1] = __builtin_amdgcn_mfma_f32_32x32x16_bf16(af0, w1c, acc[0][1], 0, 0, 0);
            acc[1][0] = __builtin_amdgcn_mfma_f32_32x32x16_bf16(af1, w0c, acc[1][0], 0, 0, 0);
            acc[1][1] = __builtin_amdgcn_mfma_f32_32x32x16_bf16(af1, w1c, acc[1][1], 0, 0, 0);
        }
        // tail: consume the last 4 ring entries, no prefetch
#pragma unroll
        for (int kk = 60; kk < 64; ++kk) {
            const int cur = kk & 3;
            const int oc  = kk * 2 + half;
            bf16x8 af0 = *(const bf16x8*)(&As[rl * 1024 + ((oc ^ rl) << 3)]);
            bf16x8 af1 = *(const bf16x8*)(&As[(32 + rl) * 1024 + ((oc ^ rl) << 3)]);
            acc[0][0] = __builtin_amdgcn_mfma_f32_32x32x16_bf16(af0, wf0[cur], acc[0][0], 0, 0, 0);
            acc[0][1] = __builtin_amdgcn_mfma_f32_32x32x16_bf16(af0, wf1[cur], acc[0][1], 0, 0, 0);
            acc[1][0] = __builtin_amdgcn_mfma_f32_32x32x16_bf16(af1, wf0[cur], acc[1][0], 0, 0, 0);
            acc[1][1] = __builtin_amdgcn_mfma_f32_32x32x16_bf16(af1, wf1[cur], acc[1][1], 0, 0, 0);
        }

        // fold this pass: relu(h + b0) dot W2 into persistent rowpart regs
#pragma unroll
        for (int ti = 0; ti < 2; ++ti)
#pragma unroll
            for (int r = 0; r < 16; ++r)
                rowpart[ti][r] += fmaxf(acc[ti][0][r] + b0a, 0.f) * w2a
                                + fmaxf(acc[ti][1][r] + b0b, 0.f) * w2b;
    }

    // ---- final: shuffle-reduce over 32 col-lanes, cross-wave sum via LDS ----
    // C/D layout (m74/m101): col = lane&31, row = (r&3) + 8*(r>>2) + 4*half
#pragma unroll
    for (int ti = 0; ti < 2; ++ti)
#pragma unroll
        for (int r = 0; r < 16; ++r) {
            float p = rowpart[ti][r];
#pragma unroll
            for (int m = 1; m <= 16; m <<= 1)
                p += __shfl_xor(p, m, 64);        // stays within each 32-half
            if (rl == 0)
                red[wave][ti * 32 + (r & 3) + 8 * (r >> 2) + 4 * half] = p;
        }
    __syncthreads();
    if (tid < 64) {
        float s = 0.f;
#pragma unroll
        for (int w = 0; w < 8; ++w) s += red[w][tid];
        atomicAdd(&out[row0 + tid], s);            // 4 adds/row (quarters)
    }
}

// ---------------- legacy R5 path (ws fits wb only; proven 147us loop) --------
__global__ __launch_bounds__(512, 2) void k_strip_r5(
    const float* __restrict__ xf, const unsigned short* __restrict__ wb,
    const float* __restrict__ b0, const float* __restrict__ W2,
    const float* __restrict__ b2, float* __restrict__ out)
{
    __shared__ unsigned short As[64 * 1024];
    __shared__ float red[8][64];

    const int tid  = threadIdx.x;
    const int lane = tid & 63;
    const int wave = tid >> 6;
    const int rl   = lane & 31;
    const int half = lane >> 5;
    const int row0 = blockIdx.x * 64;

    ((float*)red)[tid] = 0.f;
    {
        const int so8 = tid & 127;
        const int rb  = tid >> 7;
        const float* xsrc = xf + (size_t)row0 * D_IN + so8 * 8;
#pragma unroll
        for (int j = 0; j < 16; ++j) {
            const int r = j * 4 + rb;
            const float* p = xsrc + (size_t)r * D_IN;
            float4 v0 = *(const float4*)(p);
            float4 v1 = *(const float4*)(p + 4);
            uint4 o;
            o.x = f2bf(v0.x) | (f2bf(v0.y) << 16);
            o.y = f2bf(v0.z) | (f2bf(v0.w) << 16);
            o.z = f2bf(v1.x) | (f2bf(v1.y) << 16);
            o.w = f2bf(v1.z) | (f2bf(v1.w) << 16);
            *(uint4*)(&As[r * 1024 + ((so8 ^ (r & 31)) << 3)]) = o;
        }
    }
    __syncthreads();

    float rowpart[2][16];
#pragma unroll
    for (int ti = 0; ti < 2; ++ti)
#pragma unroll
        for (int r = 0; r < 16; ++r) rowpart[ti][r] = 0.f;

    for (int pass = 0; pass < 8; ++pass) {
        const int n0 = wave * 64 + pass * 512;
        const float w2a = W2[n0 + rl],      b0a = b0[n0 + rl];
        const float w2b = W2[n0 + 32 + rl], b0b = b0[n0 + 32 + rl];
        const int n32 = n0 >> 5;
        const unsigned short* w0p = wb + (size_t)n32 * 32768 + half * 256 + rl * 8;
        const unsigned short* w1p = w0p + 32768;

        f32x16 acc[2][2] = {};
        bf16x8 wf0[4], wf1[4];
#pragma unroll
        for (int p = 0; p < 4; ++p) {
            wf0[p] = *(const bf16x8*)(w0p + p * 512);
            wf1[p] = *(const bf16x8*)(w1p + p * 512);
        }
#pragma unroll 4
        for (int kk = 0; kk < 60; ++kk) {
            const int cur = kk & 3;
            const int oc  = kk * 2 + half;
            bf16x8 af0 = *(const bf16x8*)(&As[rl * 1024 + ((oc ^ rl) << 3)]);
            bf16x8 af1 = *(const bf16x8*)(&As[(32 + rl) * 1024 + ((oc ^ rl) << 3)]);
            bf16x8 w0c = wf0[cur], w1c = wf1[cur];
            wf0[cur] = *(const bf16x8*)(w0p + (kk + 4) * 512);
            wf1[cur] = *(const bf16x8*)(w1p + (kk + 4) * 512);
            acc[0][0] = __builtin_amdgcn_mfma_f32_32x32x16_bf16(af0, w0c, acc[0][0], 0, 0, 0);
            acc[0][1] = __builtin_amdgcn_mfma_f32_32x32x16_bf16(af0, w1c, acc[0][1], 0, 0, 0);
            acc[1][0] = __builtin_amdgcn_mfma_f32_32x32x16_bf16(af1, w0c, acc[1][0], 0, 0, 0);
            acc[1][1] = __builtin_amdgcn_mfma_f32_32x32x16_bf16(af1, w1c, acc[1][1], 0, 0, 0);
        }
#pragma unroll
        for (int kk = 60; kk < 64; ++kk) {
            const int cur = kk & 3;
            const int oc  = kk * 2 + half;
            bf16x8 af0 = *(const bf16x8*)(&As[rl * 1024 + ((oc ^ rl) << 3)]);
            bf16x8 af1 = *(const bf16x8*)(&As[(32 + rl) * 1024 + ((oc ^ rl) << 3)]);
            acc[0][0] = __builtin_amdgcn_mfma_f32_32x32x16_bf16(af0, wf0[cur], acc[0][0], 0, 0, 0);
            acc[0][1] = __builtin_amdgcn_mfma_f32_32x32x16_bf16(af0, wf1[cur], acc[0][1], 0, 0, 0);
            acc[1][0] = __builtin_amdgcn_mfma_f32_32x32x16_bf16(af1, wf0[cur], acc[1][0], 0, 0, 0);
            acc[1][1] = __builtin_amdgcn_mfma_f32_32x32x16_bf16(af1, wf1[cur], acc[1][1], 0, 0, 0);
        }
#pragma unroll
        for (int ti = 0; ti < 2; ++ti)
#pragma unroll
            for (int r = 0; r < 16; ++r)
                rowpart[ti][r] += fmaxf(acc[ti][0][r] + b0a, 0.f) * w2a
                                + fmaxf(acc[ti][1][r] + b0b, 0.f) * w2b;
    }

#pragma unroll
    for (int ti = 0; ti < 2; ++ti)
#pragma unroll
        for (int r = 0; r < 16; ++r) {
            float p = rowpart[ti][r];
#pragma unroll
            for (int m = 1; m <= 16; m <<= 1)
                p += __shfl_xor(p, m, 64);
            if (rl == 0)
                red[wave][ti * 32 + (r & 3) + 8 * (r >> 2) + 4 * half] = p;
        }
    __syncthreads();
    if (tid < 64) {
        float s = b2[0];
#pragma unroll
        for (int w = 0; w < 8; ++w) s += red[w][tid];
        out[row0 + tid] = s;
    }
}

// ---------------- naive fallback (correctness only; ws too small) ------------
__global__ __launch_bounds__(256) void k_naive(
    const float* __restrict__ x, const float* __restrict__ W0,
    const float* __restrict__ b0, const float* __restrict__ A,
    const float* __restrict__ Bl, const float* __restrict__ W2,
    const float* __restrict__ b2, float* __restrict__ out)
{
    __shared__ float xs[D_IN];
    int b = blockIdx.x;
    for (int d = threadIdx.x; d < D_IN; d += 256) xs[d] = x[(size_t)b * D_IN + d];
    __syncthreads();
    float part = 0.f;
    for (int m = threadIdx.x; m < M_HID; m += 256) {
        float h = b0[m];
        const float* wr = W0 + (size_t)m * D_IN;
        const float* brow = Bl + m * R_LORA;
        for (int d = 0; d < D_IN; ++d) {
            float w = wr[d];
            for (int r = 0; r < R_LORA; ++r) w += SCALING * brow[r] * A[r * D_IN + d];
            h += xs[d] * w;
        }
        part += fmaxf(h, 0.f) * W2[m];
    }
    __shared__ float sred[256];
    sred[threadIdx.x] = part;
    __syncthreads();
    for (int s = 128; s > 0; s >>= 1) {
        if (threadIdx.x < s) sred[threadIdx.x] += sred[threadIdx.x + s];
        __syncthreads();
    }
    if (threadIdx.x == 0) out[b] = sred[0] + b2[0];
}

// ---------------- host ----------------
extern "C" void kernel_launch(void* const* d_in, const int* in_sizes, int n_in,
                              void* d_out, int out_size, void* d_ws, size_t ws_size,
                              hipStream_t stream) {
    const float* x  = (const float*)d_in[0];
    const float* W0 = (const float*)d_in[1];
    const float* b0 = (const float*)d_in[2];
    const float* A  = (const float*)d_in[3];
    const float* Bl = (const float*)d_in[4];
    const float* W2 = (const float*)d_in[5];
    const float* b2 = (const float*)d_in[6];
    float* out = (float*)d_out;

    const size_t wb_bytes = (size_t)M_HID * D_IN * 2;   // 8 MiB fragment-ordered W_eff
    const size_t q_bytes  = 4 * sizeof(int);            // per-quarter ticket counters

    if (ws_size >= wb_bytes + q_bytes) {
        unsigned short* wb = (unsigned short*)d_ws;
        int* qctr = (int*)((char*)d_ws + wb_bytes);
        hipLaunchKernelGGL(k_wprep, dim3(M_HID / 32 * 2), dim3(512), 0, stream,
                           W0, A, Bl, b2, wb, out, qctr);
        hipLaunchKernelGGL(k_strip, dim3(1024), dim3(512), 0, stream,
                           x, wb, b0, W2, out, qctr);
    } else if (ws_size >= wb_bytes) {
        unsigned short* wb = (unsigned short*)d_ws;
        hipLaunchKernelGGL(k_wprep, dim3(M_HID / 32 * 2), dim3(512), 0, stream,
                           W0, A, Bl, b2, wb, out, (int*)nullptr);
        hipLaunchKernelGGL(k_strip_r5, dim3(BATCH / 64), dim3(512), 0, stream,
                           x, wb, b0, W2, b2, out);
    } else {
        hipLaunchKernelGGL(k_naive, dim3(BATCH), dim3(256), 0, stream,
                           x, W0, b0, A, Bl, W2, b2, out);
    }
}